// Round 1
// baseline (111.010 us; speedup 1.0000x reference)
//
#include <hip/hip_runtime.h>
#include <math.h>

#define NB 128
#define NM 32
#define NN 64
#define NK 2048
#define NP (NN + NK - 1)   // 2111
#define HALF0 1056         // p in [0,1056) for half 0, [1056,2111) for half 1

__global__ __launch_bounds__(256) void gen_cell_kernel(
    const float* __restrict__ qt1,
    const float* __restrict__ ht1,
    const float* __restrict__ zt,
    const float* __restrict__ alpha_t,
    const float* __restrict__ conv_w,
    const float* __restrict__ conv_b,
    const float* __restrict__ W_xr, const float* __restrict__ W_hr, const float* __restrict__ b_r,
    const float* __restrict__ W_xu, const float* __restrict__ W_hu, const float* __restrict__ b_u,
    const float* __restrict__ W_xn, const float* __restrict__ W_hn, const float* __restrict__ b_n,
    const float* __restrict__ lin_w, const float* __restrict__ lin_b,
    const float* __restrict__ W_emb,
    float* __restrict__ out)
{
    const int b    = blockIdx.x >> 1;
    const int half = blockIdx.x & 1;
    const int tid  = threadIdx.x;

    __shared__ __align__(16) float s_w[2 * NK];     // staged W_emb, 16 KB, [k*2+c]
    __shared__ __align__(16) float s_f[2 * HALF0];  // this block's f_srt slice
    __shared__ __align__(16) float s_ht[2 * NN];
    __shared__ float s_s[NN];

    // stage W_emb -> LDS (1024 float4, coalesced)
    {
        const float4* src = (const float4*)W_emb;
        float4* dst = (float4*)s_w;
        #pragma unroll
        for (int i = 0; i < 4; ++i) dst[tid + 256 * i] = src[tid + 256 * i];
    }

    float* st_out = out;                              // [B,N,2]
    float* qt_out = out + NB * NN * 2;                // [B,M,N,2]
    float* ht_out = out + NB * NN * 2 + NB * NM * NN * 2; // [B,N,2]

    // ---- Stage 1: Ht1 conv + GRU gates (threads 0..63, one per n) ----
    if (tid < NN) {
        const int n = tid;
        const float* q = qt1 + (size_t)b * (NM * NN * 2) + n * 2;
        float h0 = conv_b[0], h1 = conv_b[1];
        #pragma unroll
        for (int h = 0; h < NM; ++h) {
            float m0 = q[h * (NN * 2)];
            float m1 = q[h * (NN * 2) + 1];
            h0 = fmaf(m0, conv_w[h],      fmaf(m1, conv_w[33 + h], h0));
            h1 = fmaf(m0, conv_w[66 + h], fmaf(m1, conv_w[99 + h], h1));
        }
        const float hp0 = ht1[b * (NN * 2) + n * 2];
        const float hp1 = ht1[b * (NN * 2) + n * 2 + 1];
        h0 = fmaf(hp0, conv_w[32],      fmaf(hp1, conv_w[33 + 32], h0));
        h1 = fmaf(hp0, conv_w[66 + 32], fmaf(hp1, conv_w[99 + 32], h1));

        const float x0 = zt[b * NN + n];
        const float x1 = alpha_t[b * NN + n];

        float pr0 = x0*W_xr[0] + x1*W_xr[2] + h0*W_hr[0] + h1*W_hr[2] + b_r[0];
        float pr1 = x0*W_xr[1] + x1*W_xr[3] + h0*W_hr[1] + h1*W_hr[3] + b_r[1];
        float r0 = 1.f / (1.f + expf(-pr0));
        float r1 = 1.f / (1.f + expf(-pr1));

        float pu0 = x0*W_xu[0] + x1*W_xu[2] + h0*W_hu[0] + h1*W_hu[2] + b_u[0];
        float pu1 = x0*W_xu[1] + x1*W_xu[3] + h0*W_hu[1] + h1*W_hu[3] + b_u[1];
        float u0 = 1.f / (1.f + expf(-pu0));
        float u1 = 1.f / (1.f + expf(-pu1));

        float g0 = r0 * h0, g1 = r1 * h1;
        float pn0 = x0*W_xn[0] + x1*W_xn[2] + g0*W_hn[0] + g1*W_hn[2] + b_n[0];
        float pn1 = x0*W_xn[1] + x1*W_xn[3] + g0*W_hn[1] + g1*W_hn[3] + b_n[1];
        float nt0 = tanhf(pn0);
        float nt1 = tanhf(pn1);

        float ho0 = u0 * hp0 + (1.f - u0) * nt0;
        float ho1 = u1 * hp1 + (1.f - u1) * nt1;
        s_ht[n * 2]     = ho0;
        s_ht[n * 2 + 1] = ho1;
        if (half == 0) {
            ht_out[b * (NN * 2) + n * 2]     = ho0;
            ht_out[b * (NN * 2) + n * 2 + 1] = ho1;
        }
    }
    __syncthreads();

    // ---- Stage 2: it = ht_flat @ lin_w[n] + lin_b; s = it * alpha ----
    if (tid < NN) {
        const int n = tid;
        float acc = lin_b[n];
        const float4* lw4 = (const float4*)(lin_w + n * (2 * NN));
        const float4* h4  = (const float4*)s_ht;
        #pragma unroll
        for (int j = 0; j < 32; ++j) {
            float4 lw = lw4[j];
            float4 hv = h4[j];
            acc = fmaf(lw.x, hv.x, acc);
            acc = fmaf(lw.y, hv.y, acc);
            acc = fmaf(lw.z, hv.z, acc);
            acc = fmaf(lw.w, hv.w, acc);
        }
        s_s[n] = acc * alpha_t[b * NN + n];
    }
    __syncthreads();

    // ---- Stage 3: overlap-add FIR f[p,c] = sum_n s[n] * W_emb[p-n,c] ----
    const int plo = half ? HALF0 : 0;
    const int phi = half ? NP : HALF0;
    const float2* w2 = (const float2*)s_w;
    for (int p = plo + tid; p < phi; p += 256) {
        int nlo = p - (NK - 1); nlo = nlo < 0 ? 0 : nlo;
        int nhi = p < NN - 1 ? p : NN - 1;
        float a0 = 0.f, a1 = 0.f;
        for (int n = nlo; n <= nhi; ++n) {
            float sv = s_s[n];       // wave-uniform broadcast
            float2 wv = w2[p - n];   // stride-1 float2 across lanes
            a0 = fmaf(sv, wv.x, a0);
            a1 = fmaf(sv, wv.y, a1);
        }
        s_f[(p - plo) * 2]     = a0;
        s_f[(p - plo) * 2 + 1] = a1;
    }
    __syncthreads();

    // ---- Stage 4: outputs ----
    // st = qt1[:,0] + f[:N]  (block half 0 owns f flat [0,2112))
    if (half == 0 && tid < 128) {
        st_out[b * 128 + tid] = qt1[(size_t)b * 4096 + tid] + s_f[tid];
    }
    // qt flat x in [0,4096): val = (x<3968 ? qt1[b,128+x] : 0) + (x<4094 ? f[128+x] : 0)
    // half 0 covers x in [0,1984) (f flat [128,2112)); half 1 covers x in [1984,4096)
    {
        const float* qb = qt1 + (size_t)b * 4096;
        float* ob = qt_out + (size_t)b * 4096;
        const int ilo = half ? 496 : 0;
        const int ihi = half ? 1024 : 496;
        const int fofs = 128 - 2 * plo;  // f-flat -> local LDS offset
        for (int i = ilo + tid; i < ihi; i += 256) {
            int x = i * 4;
            float4 v;
            if (x <= 3964) {
                const float4 qv = *(const float4*)(qb + 128 + x);
                const float4 fv = *(const float4*)(s_f + fofs + x);
                v.x = qv.x + fv.x; v.y = qv.y + fv.y;
                v.z = qv.z + fv.z; v.w = qv.w + fv.w;
            } else {
                float tmp[4];
                #pragma unroll
                for (int c = 0; c < 4; ++c) {
                    int xx = x + c;
                    float qv = (xx < 3968) ? qb[128 + xx] : 0.f;
                    float fv = (xx < 4094) ? s_f[fofs + xx] : 0.f;
                    tmp[c] = qv + fv;
                }
                v.x = tmp[0]; v.y = tmp[1]; v.z = tmp[2]; v.w = tmp[3];
            }
            *(float4*)(ob + x) = v;
        }
    }
}

extern "C" void kernel_launch(void* const* d_in, const int* in_sizes, int n_in,
                              void* d_out, int out_size, void* d_ws, size_t ws_size,
                              hipStream_t stream) {
    (void)in_sizes; (void)n_in; (void)out_size; (void)d_ws; (void)ws_size;
    gen_cell_kernel<<<dim3(NB * 2), dim3(256), 0, stream>>>(
        (const float*)d_in[0],  (const float*)d_in[1],  (const float*)d_in[2],
        (const float*)d_in[3],  (const float*)d_in[4],  (const float*)d_in[5],
        (const float*)d_in[6],  (const float*)d_in[7],  (const float*)d_in[8],
        (const float*)d_in[9],  (const float*)d_in[10], (const float*)d_in[11],
        (const float*)d_in[12], (const float*)d_in[13], (const float*)d_in[14],
        (const float*)d_in[15], (const float*)d_in[16], (const float*)d_in[17],
        (float*)d_out);
}

// Round 2
// 100.254 us; speedup vs baseline: 1.1073x; 1.1073x over previous
//
#include <hip/hip_runtime.h>
#include <math.h>

#define NB 128
#define NM 32
#define NN 64
#define NK 2048
#define NP (NN + NK - 1)   // 2111
#define HALF0 1056         // p in [0,1056) for half 0, [1056,2111) for half 1
#define NR 2176            // reversed+padded W length (float2 entries): [0,64)=0, [64,2112)=w[2111-i], [2112,2176)=0

__global__ __launch_bounds__(256) void gen_cell_kernel(
    const float* __restrict__ qt1,
    const float* __restrict__ ht1,
    const float* __restrict__ zt,
    const float* __restrict__ alpha_t,
    const float* __restrict__ conv_w,
    const float* __restrict__ conv_b,
    const float* __restrict__ W_xr, const float* __restrict__ W_hr, const float* __restrict__ b_r,
    const float* __restrict__ W_xu, const float* __restrict__ W_hu, const float* __restrict__ b_u,
    const float* __restrict__ W_xn, const float* __restrict__ W_hn, const float* __restrict__ b_n,
    const float* __restrict__ lin_w, const float* __restrict__ lin_b,
    const float* __restrict__ W_emb,
    float* __restrict__ out)
{
    const int b    = blockIdx.x >> 1;
    const int half = blockIdx.x & 1;
    const int tid  = threadIdx.x;

    __shared__ __align__(16) float2 s_wr[NR];       // reversed+padded W_emb, 17 KB
    __shared__ __align__(16) float s_f[2 * HALF0];  // this block's f_srt slice
    __shared__ __align__(16) float s_ht[2 * NN];
    __shared__ float s_s[NN];

    // stage W_emb reversed + zero-padded: s_wr[i] = w2[2111-i] for i in [64,2112), else 0
    {
        const float2* w2g = (const float2*)W_emb;
        float2 z2; z2.x = 0.f; z2.y = 0.f;
        for (int i = tid; i < NR; i += 256) {
            float2 v = (i >= 64 && i < 2112) ? w2g[NP - i] : z2;
            s_wr[i] = v;
        }
    }

    float* st_out = out;                                  // [B,N,2]
    float* qt_out = out + NB * NN * 2;                    // [B,M,N,2]
    float* ht_out = out + NB * NN * 2 + NB * NM * NN * 2; // [B,N,2]

    // ---- Stage 1: Ht1 conv + GRU gates (threads 0..63, one per n) ----
    if (tid < NN) {
        const int n = tid;
        const float* q = qt1 + (size_t)b * (NM * NN * 2) + n * 2;
        float h0 = conv_b[0], h1 = conv_b[1];
        #pragma unroll
        for (int h = 0; h < NM; ++h) {
            float m0 = q[h * (NN * 2)];
            float m1 = q[h * (NN * 2) + 1];
            h0 = fmaf(m0, conv_w[h],      fmaf(m1, conv_w[33 + h], h0));
            h1 = fmaf(m0, conv_w[66 + h], fmaf(m1, conv_w[99 + h], h1));
        }
        const float hp0 = ht1[b * (NN * 2) + n * 2];
        const float hp1 = ht1[b * (NN * 2) + n * 2 + 1];
        h0 = fmaf(hp0, conv_w[32],      fmaf(hp1, conv_w[33 + 32], h0));
        h1 = fmaf(hp0, conv_w[66 + 32], fmaf(hp1, conv_w[99 + 32], h1));

        const float x0 = zt[b * NN + n];
        const float x1 = alpha_t[b * NN + n];

        float pr0 = x0*W_xr[0] + x1*W_xr[2] + h0*W_hr[0] + h1*W_hr[2] + b_r[0];
        float pr1 = x0*W_xr[1] + x1*W_xr[3] + h0*W_hr[1] + h1*W_hr[3] + b_r[1];
        float r0 = 1.f / (1.f + expf(-pr0));
        float r1 = 1.f / (1.f + expf(-pr1));

        float pu0 = x0*W_xu[0] + x1*W_xu[2] + h0*W_hu[0] + h1*W_hu[2] + b_u[0];
        float pu1 = x0*W_xu[1] + x1*W_xu[3] + h0*W_hu[1] + h1*W_hu[3] + b_u[1];
        float u0 = 1.f / (1.f + expf(-pu0));
        float u1 = 1.f / (1.f + expf(-pu1));

        float g0 = r0 * h0, g1 = r1 * h1;
        float pn0 = x0*W_xn[0] + x1*W_xn[2] + g0*W_hn[0] + g1*W_hn[2] + b_n[0];
        float pn1 = x0*W_xn[1] + x1*W_xn[3] + g0*W_hn[1] + g1*W_hn[3] + b_n[1];
        float nt0 = tanhf(pn0);
        float nt1 = tanhf(pn1);

        float ho0 = u0 * hp0 + (1.f - u0) * nt0;
        float ho1 = u1 * hp1 + (1.f - u1) * nt1;
        s_ht[n * 2]     = ho0;
        s_ht[n * 2 + 1] = ho1;
        if (half == 0) {
            ht_out[b * (NN * 2) + n * 2]     = ho0;
            ht_out[b * (NN * 2) + n * 2 + 1] = ho1;
        }
    }
    __syncthreads();

    // ---- Stage 2: it = ht_flat @ lin_w[n] + lin_b; s = it * alpha ----
    if (tid < NN) {
        const int n = tid;
        float acc = lin_b[n];
        const float4* lw4 = (const float4*)(lin_w + n * (2 * NN));
        const float4* h4  = (const float4*)s_ht;
        #pragma unroll
        for (int j = 0; j < 32; ++j) {
            float4 lw = lw4[j];
            float4 hv = h4[j];
            acc = fmaf(lw.x, hv.x, acc);
            acc = fmaf(lw.y, hv.y, acc);
            acc = fmaf(lw.z, hv.z, acc);
            acc = fmaf(lw.w, hv.w, acc);
        }
        s_s[n] = acc * alpha_t[b * NN + n];
    }
    __syncthreads();

    // ---- Stage 3: FIR, fixed-trip 64, register-blocked 4 positions/thread ----
    // f[p] = sum_{n=0}^{63} s[n] * w[p-n]  ==  sum_n s[n] * R[(2111-p) + n]
    const int plo = half ? HALF0 : 0;
    {
        const int p0 = plo + tid;                    // positions p0 + 256*j, j=0..3
        const float2* R0 = s_wr + (NP - p0);
        const float2* R1 = R0 - 256;
        const float2* R2p = R0 - 512;
        const float2* R3 = R0 - 768;
        float a00 = 0.f, a01 = 0.f, a10 = 0.f, a11 = 0.f;
        float a20 = 0.f, a21 = 0.f, a30 = 0.f, a31 = 0.f;
        #pragma unroll 8
        for (int n = 0; n < NN; ++n) {
            float sv = s_s[n];
            float2 w0 = R0[n];
            float2 w1 = R1[n];
            float2 w2v = R2p[n];
            float2 w3 = R3[n];
            a00 = fmaf(sv, w0.x, a00); a01 = fmaf(sv, w0.y, a01);
            a10 = fmaf(sv, w1.x, a10); a11 = fmaf(sv, w1.y, a11);
            a20 = fmaf(sv, w2v.x, a20); a21 = fmaf(sv, w2v.y, a21);
            a30 = fmaf(sv, w3.x, a30); a31 = fmaf(sv, w3.y, a31);
        }
        s_f[tid * 2]              = a00; s_f[tid * 2 + 1]              = a01;
        s_f[(tid + 256) * 2]      = a10; s_f[(tid + 256) * 2 + 1]      = a11;
        s_f[(tid + 512) * 2]      = a20; s_f[(tid + 512) * 2 + 1]      = a21;
        s_f[(tid + 768) * 2]      = a30; s_f[(tid + 768) * 2 + 1]      = a31;
        // tail: positions plo+1024 .. plo+1055
        if (tid < 32) {
            const int p = plo + 1024 + tid;
            const float2* Rt = s_wr + (NP - p);
            float t0 = 0.f, t1 = 0.f;
            #pragma unroll 8
            for (int n = 0; n < NN; ++n) {
                float sv = s_s[n];
                float2 wv = Rt[n];
                t0 = fmaf(sv, wv.x, t0);
                t1 = fmaf(sv, wv.y, t1);
            }
            s_f[(1024 + tid) * 2]     = t0;
            s_f[(1024 + tid) * 2 + 1] = t1;
        }
    }
    __syncthreads();

    // ---- Stage 4: outputs ----
    // st = qt1[:,0] + f[:N]  (block half 0 owns f flat [0,2112))
    if (half == 0 && tid < 128) {
        st_out[b * 128 + tid] = qt1[(size_t)b * 4096 + tid] + s_f[tid];
    }
    // qt flat x in [0,4096): val = (x<3968 ? qt1[b,128+x] : 0) + (x<4094 ? f[128+x] : 0)
    // half 0 covers x in [0,1984) (f flat [128,2112)); half 1 covers x in [1984,4096)
    {
        const float* qb = qt1 + (size_t)b * 4096;
        float* ob = qt_out + (size_t)b * 4096;
        const int ilo = half ? 496 : 0;
        const int ihi = half ? 1024 : 496;
        const int fofs = 128 - 2 * plo;  // f-flat -> local LDS offset
        for (int i = ilo + tid; i < ihi; i += 256) {
            int x = i * 4;
            float4 v;
            if (x <= 3964) {
                const float4 qv = *(const float4*)(qb + 128 + x);
                const float4 fv = *(const float4*)(s_f + fofs + x);
                v.x = qv.x + fv.x; v.y = qv.y + fv.y;
                v.z = qv.z + fv.z; v.w = qv.w + fv.w;
            } else {
                float tmp[4];
                #pragma unroll
                for (int c = 0; c < 4; ++c) {
                    int xx = x + c;
                    float qv = (xx < 3968) ? qb[128 + xx] : 0.f;
                    float fv = (xx < 4094) ? s_f[fofs + xx] : 0.f;
                    tmp[c] = qv + fv;
                }
                v.x = tmp[0]; v.y = tmp[1]; v.z = tmp[2]; v.w = tmp[3];
            }
            *(float4*)(ob + x) = v;
        }
    }
}

extern "C" void kernel_launch(void* const* d_in, const int* in_sizes, int n_in,
                              void* d_out, int out_size, void* d_ws, size_t ws_size,
                              hipStream_t stream) {
    (void)in_sizes; (void)n_in; (void)out_size; (void)d_ws; (void)ws_size;
    gen_cell_kernel<<<dim3(NB * 2), dim3(256), 0, stream>>>(
        (const float*)d_in[0],  (const float*)d_in[1],  (const float*)d_in[2],
        (const float*)d_in[3],  (const float*)d_in[4],  (const float*)d_in[5],
        (const float*)d_in[6],  (const float*)d_in[7],  (const float*)d_in[8],
        (const float*)d_in[9],  (const float*)d_in[10], (const float*)d_in[11],
        (const float*)d_in[12], (const float*)d_in[13], (const float*)d_in[14],
        (const float*)d_in[15], (const float*)d_in[16], (const float*)d_in[17],
        (float*)d_out);
}

// Round 3
// 99.921 us; speedup vs baseline: 1.1110x; 1.0033x over previous
//
#include <hip/hip_runtime.h>
#include <math.h>

#define NB 128
#define NM 32
#define NN 64
#define NK 2048
#define NP (NN + NK - 1)   // 2111
#define NQ 4               // blocks per batch
#define QSZ 528            // positions per block (4*528 = 2112 >= 2111)
#define WSPAN 592          // staged reversed-W window (float2): span 591, +1 slack

__global__ __launch_bounds__(256) void gen_cell_kernel(
    const float* __restrict__ qt1,
    const float* __restrict__ ht1,
    const float* __restrict__ zt,
    const float* __restrict__ alpha_t,
    const float* __restrict__ conv_w,
    const float* __restrict__ conv_b,
    const float* __restrict__ W_xr, const float* __restrict__ W_hr, const float* __restrict__ b_r,
    const float* __restrict__ W_xu, const float* __restrict__ W_hu, const float* __restrict__ b_u,
    const float* __restrict__ W_xn, const float* __restrict__ W_hn, const float* __restrict__ b_n,
    const float* __restrict__ lin_w, const float* __restrict__ lin_b,
    const float* __restrict__ W_emb,
    float* __restrict__ out)
{
    const int b   = blockIdx.x >> 2;
    const int q   = blockIdx.x & 3;
    const int tid = threadIdx.x;
    const int plo = q * QSZ;

    __shared__ __align__(16) float2 s_wr[WSPAN];     // reversed W window, ~4.7 KB
    __shared__ __align__(16) float s_f[2 * QSZ];     // this block's f_srt slice, 4.2 KB
    __shared__ __align__(16) float s_ht[2 * NN];
    __shared__ float s_s[NN];

    // Stage reversed+padded W window. Global reversed index i in [i_min, i_min+591),
    // where R[i] = (64 <= i < 2112) ? w2[NP - i] : 0,  i_min = 1584 - plo.
    {
        const float2* w2g = (const float2*)W_emb;
        const int i_min = 1584 - plo;
        float2 z2; z2.x = 0.f; z2.y = 0.f;
        for (int j = tid; j < 591; j += 256) {
            int i = i_min + j;
            float2 v = (i >= 64 && i < 2112) ? w2g[NP - i] : z2;
            s_wr[j] = v;
        }
    }

    float* st_out = out;                                  // [B,N,2]
    float* qt_out = out + NB * NN * 2;                    // [B,M,N,2]
    float* ht_out = out + NB * NN * 2 + NB * NM * NN * 2; // [B,N,2]

    // ---- Stage 1: Ht1 conv + GRU gates (threads 0..63, one per n) ----
    if (tid < NN) {
        const int n = tid;
        const float* qp = qt1 + (size_t)b * (NM * NN * 2) + n * 2;
        float h0 = conv_b[0], h1 = conv_b[1];
        #pragma unroll
        for (int h = 0; h < NM; ++h) {
            float m0 = qp[h * (NN * 2)];
            float m1 = qp[h * (NN * 2) + 1];
            h0 = fmaf(m0, conv_w[h],      fmaf(m1, conv_w[33 + h], h0));
            h1 = fmaf(m0, conv_w[66 + h], fmaf(m1, conv_w[99 + h], h1));
        }
        const float hp0 = ht1[b * (NN * 2) + n * 2];
        const float hp1 = ht1[b * (NN * 2) + n * 2 + 1];
        h0 = fmaf(hp0, conv_w[32],      fmaf(hp1, conv_w[33 + 32], h0));
        h1 = fmaf(hp0, conv_w[66 + 32], fmaf(hp1, conv_w[99 + 32], h1));

        const float x0 = zt[b * NN + n];
        const float x1 = alpha_t[b * NN + n];

        float pr0 = x0*W_xr[0] + x1*W_xr[2] + h0*W_hr[0] + h1*W_hr[2] + b_r[0];
        float pr1 = x0*W_xr[1] + x1*W_xr[3] + h0*W_hr[1] + h1*W_hr[3] + b_r[1];
        float r0 = 1.f / (1.f + expf(-pr0));
        float r1 = 1.f / (1.f + expf(-pr1));

        float pu0 = x0*W_xu[0] + x1*W_xu[2] + h0*W_hu[0] + h1*W_hu[2] + b_u[0];
        float pu1 = x0*W_xu[1] + x1*W_xu[3] + h0*W_hu[1] + h1*W_hu[3] + b_u[1];
        float u0 = 1.f / (1.f + expf(-pu0));
        float u1 = 1.f / (1.f + expf(-pu1));

        float g0 = r0 * h0, g1 = r1 * h1;
        float pn0 = x0*W_xn[0] + x1*W_xn[2] + g0*W_hn[0] + g1*W_hn[2] + b_n[0];
        float pn1 = x0*W_xn[1] + x1*W_xn[3] + g0*W_hn[1] + g1*W_hn[3] + b_n[1];
        float nt0 = tanhf(pn0);
        float nt1 = tanhf(pn1);

        float ho0 = u0 * hp0 + (1.f - u0) * nt0;
        float ho1 = u1 * hp1 + (1.f - u1) * nt1;
        s_ht[n * 2]     = ho0;
        s_ht[n * 2 + 1] = ho1;
        if (q == 0) {
            ht_out[b * (NN * 2) + n * 2]     = ho0;
            ht_out[b * (NN * 2) + n * 2 + 1] = ho1;
        }
    }
    __syncthreads();

    // ---- Stage 2: it = ht_flat @ lin_w[n] + lin_b; s = it * alpha ----
    if (tid < NN) {
        const int n = tid;
        float acc = lin_b[n];
        const float4* lw4 = (const float4*)(lin_w + n * (2 * NN));
        const float4* h4  = (const float4*)s_ht;
        #pragma unroll
        for (int j = 0; j < 32; ++j) {
            float4 lw = lw4[j];
            float4 hv = h4[j];
            acc = fmaf(lw.x, hv.x, acc);
            acc = fmaf(lw.y, hv.y, acc);
            acc = fmaf(lw.z, hv.z, acc);
            acc = fmaf(lw.w, hv.w, acc);
        }
        s_s[n] = acc * alpha_t[b * NN + n];
    }
    __syncthreads();

    // ---- Stage 3: FIR quarter, fixed-trip 64, 2 positions/thread + tail ----
    // f[p] = sum_n s[n]*w[p-n] = sum_n s[n]*R_local[(plo+527-p) + n]
    {
        const float2* R0 = s_wr + (527 - tid);          // p = plo + tid
        const float2* R1 = R0 - 256;                    // p = plo + tid + 256
        float a00 = 0.f, a01 = 0.f, a10 = 0.f, a11 = 0.f;
        #pragma unroll 8
        for (int n = 0; n < NN; ++n) {
            float sv = s_s[n];
            float2 w0 = R0[n];
            float2 w1 = R1[n];
            a00 = fmaf(sv, w0.x, a00); a01 = fmaf(sv, w0.y, a01);
            a10 = fmaf(sv, w1.x, a10); a11 = fmaf(sv, w1.y, a11);
        }
        s_f[tid * 2]             = a00; s_f[tid * 2 + 1]             = a01;
        s_f[(tid + 256) * 2]     = a10; s_f[(tid + 256) * 2 + 1]     = a11;
        // tail: local positions 512..527
        if (tid < 16 && (plo + 512 + tid) < NP) {
            const float2* Rt = s_wr + (527 - 512 - tid);
            float t0 = 0.f, t1 = 0.f;
            #pragma unroll 8
            for (int n = 0; n < NN; ++n) {
                float sv = s_s[n];
                float2 wv = Rt[n];
                t0 = fmaf(sv, wv.x, t0);
                t1 = fmaf(sv, wv.y, t1);
            }
            s_f[(512 + tid) * 2]     = t0;
            s_f[(512 + tid) * 2 + 1] = t1;
        }
    }
    __syncthreads();

    // ---- Stage 4: outputs ----
    // st = qt1[:,0] + f[:128]  (block q=0 owns f_flat [0,1056))
    if (q == 0 && tid < 128) {
        st_out[b * 128 + tid] = qt1[(size_t)b * 4096 + tid] + s_f[tid];
    }
    // qt flat x: val = (x<3968 ? qt1[b,128+x] : 0) + (x<4094 ? f_flat[128+x] : 0)
    // block q owns f_flat [q*1056, q*1056+1056) -> x in [q*1056-128, q*1056+928) clamped to [0,4096)
    {
        const float* qb = qt1 + (size_t)b * 4096;
        float* ob = qt_out + (size_t)b * 4096;
        const int ilo = (q == 0) ? 0 : (q * 1056 - 128) / 4;
        const int ihi = (q == 3) ? 1024 : (q * 1056 + 928) / 4;
        const int fofs = 128 - 2 * plo;  // f_flat -> local LDS float offset
        for (int i = ilo + tid; i < ihi; i += 256) {
            int x = i * 4;
            float4 v;
            if (x <= 3964) {
                const float4 qv = *(const float4*)(qb + 128 + x);
                const float4 fv = *(const float4*)(s_f + fofs + x);
                v.x = qv.x + fv.x; v.y = qv.y + fv.y;
                v.z = qv.z + fv.z; v.w = qv.w + fv.w;
            } else {
                float tmp[4];
                #pragma unroll
                for (int c = 0; c < 4; ++c) {
                    int xx = x + c;
                    float qv = (xx < 3968) ? qb[128 + xx] : 0.f;
                    float fv = (xx < 4094) ? s_f[fofs + xx] : 0.f;
                    tmp[c] = qv + fv;
                }
                v.x = tmp[0]; v.y = tmp[1]; v.z = tmp[2]; v.w = tmp[3];
            }
            *(float4*)(ob + x) = v;
        }
    }
}

extern "C" void kernel_launch(void* const* d_in, const int* in_sizes, int n_in,
                              void* d_out, int out_size, void* d_ws, size_t ws_size,
                              hipStream_t stream) {
    (void)in_sizes; (void)n_in; (void)out_size; (void)d_ws; (void)ws_size;
    gen_cell_kernel<<<dim3(NB * NQ), dim3(256), 0, stream>>>(
        (const float*)d_in[0],  (const float*)d_in[1],  (const float*)d_in[2],
        (const float*)d_in[3],  (const float*)d_in[4],  (const float*)d_in[5],
        (const float*)d_in[6],  (const float*)d_in[7],  (const float*)d_in[8],
        (const float*)d_in[9],  (const float*)d_in[10], (const float*)d_in[11],
        (const float*)d_in[12], (const float*)d_in[13], (const float*)d_in[14],
        (const float*)d_in[15], (const float*)d_in[16], (const float*)d_in[17],
        (float*)d_out);
}

// Round 4
// 98.860 us; speedup vs baseline: 1.1229x; 1.0107x over previous
//
#include <hip/hip_runtime.h>
#include <math.h>

#define NB 128
#define NM 32
#define NN 64
#define NK 2048
#define NP (NN + NK - 1)   // 2111 float2 positions
#define NQ 4               // blocks per batch
#define QSZ 528            // positions per block (4*528 = 2112 >= 2111)
#define WSPAN 592          // staged reversed-W window (float2 entries)

__global__ __launch_bounds__(256) void gen_cell_kernel(
    const float* __restrict__ qt1,
    const float* __restrict__ ht1,
    const float* __restrict__ zt,
    const float* __restrict__ alpha_t,
    const float* __restrict__ conv_w,
    const float* __restrict__ conv_b,
    const float* __restrict__ W_xr, const float* __restrict__ W_hr, const float* __restrict__ b_r,
    const float* __restrict__ W_xu, const float* __restrict__ W_hu, const float* __restrict__ b_u,
    const float* __restrict__ W_xn, const float* __restrict__ W_hn, const float* __restrict__ b_n,
    const float* __restrict__ lin_w, const float* __restrict__ lin_b,
    const float* __restrict__ W_emb,
    float* __restrict__ out)
{
    const int b   = blockIdx.x >> 2;
    const int q   = blockIdx.x & 3;
    const int tid = threadIdx.x;
    const int plo = q * QSZ;

    __shared__ __align__(16) float2 s_wr[WSPAN];  // reversed W window, ~4.7 KB
    __shared__ __align__(16) float s_ht[2 * NN];
    __shared__ float s_s[NN];

    // Stage reversed+padded W window: R_global[i] = (64<=i<2112) ? w2[NP-i] : 0,
    // local window j in [0,591) maps to i = (1584 - plo) + j.
    {
        const float2* w2g = (const float2*)W_emb;
        const int i_min = 1584 - plo;
        float2 z2; z2.x = 0.f; z2.y = 0.f;
        for (int j = tid; j < 591; j += 256) {
            int i = i_min + j;
            float2 v = (i >= 64 && i < 2112) ? w2g[NP - i] : z2;
            s_wr[j] = v;
        }
    }

    float2* st2 = (float2*)out;                              // [B,64]
    float2* qt2 = (float2*)out + NB * NN;                    // [B,2048]
    float*  ht_out = out + NB * NN * 2 + NB * NM * NN * 2;   // [B,N,2]

    // ---- Stage 1: Ht1 conv + GRU gates (threads 0..63, one per n) ----
    if (tid < NN) {
        const int n = tid;
        const float* qp = qt1 + (size_t)b * (NM * NN * 2) + n * 2;
        float h0 = conv_b[0], h1 = conv_b[1];
        #pragma unroll
        for (int h = 0; h < NM; ++h) {
            float m0 = qp[h * (NN * 2)];
            float m1 = qp[h * (NN * 2) + 1];
            h0 = fmaf(m0, conv_w[h],      fmaf(m1, conv_w[33 + h], h0));
            h1 = fmaf(m0, conv_w[66 + h], fmaf(m1, conv_w[99 + h], h1));
        }
        const float hp0 = ht1[b * (NN * 2) + n * 2];
        const float hp1 = ht1[b * (NN * 2) + n * 2 + 1];
        h0 = fmaf(hp0, conv_w[32],      fmaf(hp1, conv_w[33 + 32], h0));
        h1 = fmaf(hp0, conv_w[66 + 32], fmaf(hp1, conv_w[99 + 32], h1));

        const float x0 = zt[b * NN + n];
        const float x1 = alpha_t[b * NN + n];

        float pr0 = x0*W_xr[0] + x1*W_xr[2] + h0*W_hr[0] + h1*W_hr[2] + b_r[0];
        float pr1 = x0*W_xr[1] + x1*W_xr[3] + h0*W_hr[1] + h1*W_hr[3] + b_r[1];
        float r0 = 1.f / (1.f + expf(-pr0));
        float r1 = 1.f / (1.f + expf(-pr1));

        float pu0 = x0*W_xu[0] + x1*W_xu[2] + h0*W_hu[0] + h1*W_hu[2] + b_u[0];
        float pu1 = x0*W_xu[1] + x1*W_xu[3] + h0*W_hu[1] + h1*W_hu[3] + b_u[1];
        float u0 = 1.f / (1.f + expf(-pu0));
        float u1 = 1.f / (1.f + expf(-pu1));

        float g0 = r0 * h0, g1 = r1 * h1;
        float pn0 = x0*W_xn[0] + x1*W_xn[2] + g0*W_hn[0] + g1*W_hn[2] + b_n[0];
        float pn1 = x0*W_xn[1] + x1*W_xn[3] + g0*W_hn[1] + g1*W_hn[3] + b_n[1];
        float nt0 = tanhf(pn0);
        float nt1 = tanhf(pn1);

        float ho0 = u0 * hp0 + (1.f - u0) * nt0;
        float ho1 = u1 * hp1 + (1.f - u1) * nt1;
        s_ht[n * 2]     = ho0;
        s_ht[n * 2 + 1] = ho1;
        if (q == 0) {
            ht_out[b * (NN * 2) + n * 2]     = ho0;
            ht_out[b * (NN * 2) + n * 2 + 1] = ho1;
        }
    }
    __syncthreads();

    // ---- Stage 2: it = ht_flat @ lin_w[n] + lin_b; s = it * alpha ----
    if (tid < NN) {
        const int n = tid;
        float acc = lin_b[n];
        const float4* lw4 = (const float4*)(lin_w + n * (2 * NN));
        const float4* h4  = (const float4*)s_ht;
        #pragma unroll
        for (int j = 0; j < 32; ++j) {
            float4 lw = lw4[j];
            float4 hv = h4[j];
            acc = fmaf(lw.x, hv.x, acc);
            acc = fmaf(lw.y, hv.y, acc);
            acc = fmaf(lw.z, hv.z, acc);
            acc = fmaf(lw.w, hv.w, acc);
        }
        s_s[n] = acc * alpha_t[b * NN + n];
    }
    __syncthreads();

    // each lane caches s[lane]; loop broadcasts via readlane (scalar pipe)
    const float s_reg = s_s[tid & 63];

    const float2* q2 = (const float2*)qt1 + (size_t)b * 2048;

    // ---- Stage 3: FIR + fused direct store ----
    // f2[p] = sum_n s[n] * w2[p-n] = sum_n s[n] * R_local[(527 - (p-plo)) + n]
    {
        const float2* R0 = s_wr + (527 - tid);   // p0 = plo + tid
        const float2* R1 = R0 - 256;             // p1 = plo + 256 + tid
        float a00 = 0.f, a01 = 0.f, a10 = 0.f, a11 = 0.f;
        #pragma unroll 16
        for (int n = 0; n < NN; ++n) {
            float sv = __uint_as_float(
                __builtin_amdgcn_readlane(__float_as_uint(s_reg), n));
            float2 w0 = R0[n];
            float2 w1 = R1[n];
            a00 = fmaf(sv, w0.x, a00); a01 = fmaf(sv, w0.y, a01);
            a10 = fmaf(sv, w1.x, a10); a11 = fmaf(sv, w1.y, a11);
        }
        // position p0 = plo + tid
        {
            const int p = plo + tid;
            float2 res; res.x = a00; res.y = a01;
            if (p < 2048) { float2 qv = q2[p]; res.x += qv.x; res.y += qv.y; }
            if (p < 64) st2[b * 64 + p] = res;
            else        qt2[(size_t)b * 2048 + p - 64] = res;
        }
        // position p1 = plo + 256 + tid  (always >= 256 > 64)
        {
            const int p = plo + 256 + tid;
            float2 res; res.x = a10; res.y = a11;
            if (p < 2048) { float2 qv = q2[p]; res.x += qv.x; res.y += qv.y; }
            qt2[(size_t)b * 2048 + p - 64] = res;
        }
        // tail position p2 = plo + 512 + tid, tid < 16
        if (tid < 16) {
            const int p = plo + 512 + tid;
            if (p < NP) {
                const float2* R2p = R0 - 512;
                float t0 = 0.f, t1 = 0.f;
                #pragma unroll 16
                for (int n = 0; n < NN; ++n) {
                    float sv = __uint_as_float(
                        __builtin_amdgcn_readlane(__float_as_uint(s_reg), n));
                    float2 wv = R2p[n];
                    t0 = fmaf(sv, wv.x, t0);
                    t1 = fmaf(sv, wv.y, t1);
                }
                float2 res; res.x = t0; res.y = t1;
                if (p < 2048) { float2 qv = q2[p]; res.x += qv.x; res.y += qv.y; }
                qt2[(size_t)b * 2048 + p - 64] = res;
            }
        }
    }

    // qt2[b][2047] has no f contribution (p=2111 doesn't exist) and no q_shift
    // (y>=1984) -> zero. One writer: block q==3, tid==0.
    if (q == 3 && tid == 0) {
        float2 z; z.x = 0.f; z.y = 0.f;
        qt2[(size_t)b * 2048 + 2047] = z;
    }
}

extern "C" void kernel_launch(void* const* d_in, const int* in_sizes, int n_in,
                              void* d_out, int out_size, void* d_ws, size_t ws_size,
                              hipStream_t stream) {
    (void)in_sizes; (void)n_in; (void)out_size; (void)d_ws; (void)ws_size;
    gen_cell_kernel<<<dim3(NB * NQ), dim3(256), 0, stream>>>(
        (const float*)d_in[0],  (const float*)d_in[1],  (const float*)d_in[2],
        (const float*)d_in[3],  (const float*)d_in[4],  (const float*)d_in[5],
        (const float*)d_in[6],  (const float*)d_in[7],  (const float*)d_in[8],
        (const float*)d_in[9],  (const float*)d_in[10], (const float*)d_in[11],
        (const float*)d_in[12], (const float*)d_in[13], (const float*)d_in[14],
        (const float*)d_in[15], (const float*)d_in[16], (const float*)d_in[17],
        (float*)d_out);
}